// Round 2
// baseline (680.511 us; speedup 1.0000x reference)
//
#include <hip/hip_runtime.h>
#include <stdint.h>

#define D_MODEL 1024
#define D_HIDDEN 4096
#define NUM_EXPERTS 8
#define NTOK 4096  // B*T = 2*2048

typedef __bf16 bf16x8 __attribute__((ext_vector_type(8)));
typedef float floatx4 __attribute__((ext_vector_type(4)));

static __device__ __forceinline__ unsigned short f2bf(float f) {
    union { float f; unsigned int i; } v;
    v.f = f;
    unsigned int i = v.i;
    unsigned int r = (i + 0x7fffu + ((i >> 16) & 1u)) >> 16;  // RNE
    return (unsigned short)r;
}

// ---------------------------------------------------------------------------
// Gating (pure fp32): one wave per token -> top-1 expert + softmax weight,
// scatter token into per-expert list.
// ---------------------------------------------------------------------------
__global__ __launch_bounds__(64) void gate_kernel(
    const float* __restrict__ x,    // [NTOK][D_MODEL]
    const float* __restrict__ Wg,   // [D_MODEL][NUM_EXPERTS]
    const float* __restrict__ bg,   // [NUM_EXPERTS]
    int* __restrict__ counts,       // [NUM_EXPERTS] (pre-zeroed)
    int* __restrict__ tlist,        // [NUM_EXPERTS][NTOK]
    float* __restrict__ wgt)        // [NTOK]
{
    const int tok = blockIdx.x;
    const int lane = threadIdx.x;

    float acc[NUM_EXPERTS];
#pragma unroll
    for (int e = 0; e < NUM_EXPERTS; e++) acc[e] = 0.f;

    const float* xr = x + (size_t)tok * D_MODEL;
    for (int d = lane; d < D_MODEL; d += 64) {
        float xv = xr[d];
        const float4* wr = (const float4*)(Wg + (size_t)d * NUM_EXPERTS);
        float4 w0 = wr[0], w1 = wr[1];
        acc[0] += xv * w0.x; acc[1] += xv * w0.y;
        acc[2] += xv * w0.z; acc[3] += xv * w0.w;
        acc[4] += xv * w1.x; acc[5] += xv * w1.y;
        acc[6] += xv * w1.z; acc[7] += xv * w1.w;
    }
#pragma unroll
    for (int e = 0; e < NUM_EXPERTS; e++) {
        float v = acc[e];
#pragma unroll
        for (int off = 32; off > 0; off >>= 1) v += __shfl_xor(v, off, 64);
        acc[e] = v;
    }
    if (lane == 0) {
        float lg[NUM_EXPERTS];
#pragma unroll
        for (int e = 0; e < NUM_EXPERTS; e++) lg[e] = acc[e] + bg[e];
        int amax = 0;
        float m = lg[0];
#pragma unroll
        for (int e = 1; e < NUM_EXPERTS; e++) {
            if (lg[e] > m) { m = lg[e]; amax = e; }  // first-index-wins
        }
        float s = 0.f;
#pragma unroll
        for (int e = 0; e < NUM_EXPERTS; e++) s += __expf(lg[e] - m);
        wgt[tok] = 1.0f / s;
        int pos = atomicAdd(&counts[amax], 1);
        tlist[amax * NTOK + pos] = tok;
    }
}

// ---------------------------------------------------------------------------
// tile-slot -> (expert, m_tile, count). Total m-tiles <= 71.
// ---------------------------------------------------------------------------
__device__ __forceinline__ bool slot_to_expert(const int* counts, int slot,
                                               int& e_out, int& mt_out, int& cnt_out) {
    int cum = 0;
    for (int i = 0; i < NUM_EXPERTS; i++) {
        int c = counts[i];
        int t = (c + 63) >> 6;
        if (slot < cum + t) {
            e_out = i; mt_out = slot - cum; cnt_out = c;
            return true;
        }
        cum += t;
    }
    return false;
}

// ---------------------------------------------------------------------------
// FFN1: h[tok] = silu( x[tok] @ W1[e] + b1[e] ), K=1024, N=4096.
// fp32 inputs converted to bf16 in-register; MFMA 16x16x32 bf16; h -> bf16.
// ---------------------------------------------------------------------------
__global__ __launch_bounds__(256) void ffn1_kernel(
    const float* __restrict__ x,     // [NTOK][D_MODEL]
    const float* __restrict__ W1,    // [E][D_MODEL][D_HIDDEN]
    const float* __restrict__ b1,    // [E][D_HIDDEN]
    const int* __restrict__ counts,
    const int* __restrict__ tlist,
    unsigned short* __restrict__ h)  // [NTOK][D_HIDDEN] bf16
{
    int e, mt, cnt;
    if (!slot_to_expert(counts, blockIdx.y, e, mt, cnt)) return;
    const int n0 = blockIdx.x * 64;

    __shared__ __align__(16) unsigned short As[64][32];  // [m][k] bf16
    __shared__ __align__(16) unsigned short Bs[64][40];  // [n][k] bf16, pad->40
    __shared__ int toks[64];

    const int tid = threadIdx.x;
    if (tid < 64) {
        int r = mt * 64 + tid;
        toks[tid] = (r < cnt) ? tlist[e * NTOK + r] : -1;
    }
    __syncthreads();

    const int wave = tid >> 6;
    const int lane = tid & 63;
    const int quad = lane >> 4;
    const int lm = lane & 15;

    floatx4 acc[4];
#pragma unroll
    for (int i = 0; i < 4; i++) acc[i] = (floatx4){0.f, 0.f, 0.f, 0.f};

    const float* W1e = W1 + (size_t)e * D_MODEL * D_HIDDEN;

    // A staging: row ar = tid/4, 8-float group ap = tid%4
    const int ar = tid >> 2, ap = tid & 3;
    int atok = toks[ar];
    const float* arow = x + (size_t)(atok < 0 ? 0 : atok) * D_MODEL + ap * 8;
    // B staging: k = tid/8, 8 consecutive n at (tid%8)*8
    const int bk = tid >> 3, bc = (tid & 7) * 8;

    for (int k0 = 0; k0 < D_MODEL; k0 += 32) {
        const float4* ap4 = (const float4*)(arow + k0);
        float4 a0 = ap4[0], a1 = ap4[1];
        unsigned short av[8] = {f2bf(a0.x), f2bf(a0.y), f2bf(a0.z), f2bf(a0.w),
                                f2bf(a1.x), f2bf(a1.y), f2bf(a1.z), f2bf(a1.w)};
        *(uint4*)(&As[ar][ap * 8]) = *(const uint4*)av;

        const float4* bp4 = (const float4*)(W1e + (size_t)(k0 + bk) * D_HIDDEN + n0 + bc);
        float4 b0 = bp4[0], b1v = bp4[1];
        unsigned short bv[8] = {f2bf(b0.x), f2bf(b0.y), f2bf(b0.z), f2bf(b0.w),
                                f2bf(b1v.x), f2bf(b1v.y), f2bf(b1v.z), f2bf(b1v.w)};
#pragma unroll
        for (int j = 0; j < 8; j++) Bs[bc + j][bk] = bv[j];  // transpose
        __syncthreads();

        bf16x8 af = *(const bf16x8*)(&As[wave * 16 + lm][quad * 8]);
#pragma unroll
        for (int ns = 0; ns < 4; ns++) {
            bf16x8 bf = *(const bf16x8*)(&Bs[ns * 16 + lm][quad * 8]);
            acc[ns] = __builtin_amdgcn_mfma_f32_16x16x32_bf16(af, bf, acc[ns], 0, 0, 0);
        }
        __syncthreads();
    }

    const float* b1e = b1 + (size_t)e * D_HIDDEN;
#pragma unroll
    for (int ns = 0; ns < 4; ns++) {
        int n = n0 + ns * 16 + lm;
        float bias = b1e[n];
#pragma unroll
        for (int r = 0; r < 4; r++) {
            int m = wave * 16 + quad * 4 + r;
            int tk = toks[m];
            if (tk >= 0) {
                float z = acc[ns][r] + bias;
                float sv = z / (1.f + __expf(-z));  // silu
                h[(size_t)tk * D_HIDDEN + n] = f2bf(sv);
            }
        }
    }
}

// ---------------------------------------------------------------------------
// FFN2: y[tok] = ( h[tok] @ W2[e] + b2[e] ) * w[tok], K=4096, N=1024.
// ---------------------------------------------------------------------------
__global__ __launch_bounds__(256) void ffn2_kernel(
    const unsigned short* __restrict__ h,  // [NTOK][D_HIDDEN] bf16
    const float* __restrict__ W2,          // [E][D_HIDDEN][D_MODEL]
    const float* __restrict__ b2,          // [E][D_MODEL]
    const int* __restrict__ counts,
    const int* __restrict__ tlist,
    const float* __restrict__ wgt,
    float* __restrict__ out)               // [NTOK][D_MODEL] fp32
{
    int e, mt, cnt;
    if (!slot_to_expert(counts, blockIdx.y, e, mt, cnt)) return;
    const int n0 = blockIdx.x * 64;

    __shared__ __align__(16) unsigned short As[64][32];
    __shared__ __align__(16) unsigned short Bs[64][40];
    __shared__ int toks[64];

    const int tid = threadIdx.x;
    if (tid < 64) {
        int r = mt * 64 + tid;
        toks[tid] = (r < cnt) ? tlist[e * NTOK + r] : -1;
    }
    __syncthreads();

    const int wave = tid >> 6;
    const int lane = tid & 63;
    const int quad = lane >> 4;
    const int lm = lane & 15;

    floatx4 acc[4];
#pragma unroll
    for (int i = 0; i < 4; i++) acc[i] = (floatx4){0.f, 0.f, 0.f, 0.f};

    const float* W2e = W2 + (size_t)e * D_HIDDEN * D_MODEL;

    const int ar = tid >> 2, ap = tid & 3;
    int atok = toks[ar];
    const unsigned short* arow =
        h + (size_t)(atok < 0 ? 0 : atok) * D_HIDDEN + ap * 8;
    const int bk = tid >> 3, bc = (tid & 7) * 8;

    for (int k0 = 0; k0 < D_HIDDEN; k0 += 32) {
        uint4 av = *(const uint4*)(arow + k0);  // h already bf16
        *(uint4*)(&As[ar][ap * 8]) = av;

        const float4* bp4 = (const float4*)(W2e + (size_t)(k0 + bk) * D_MODEL + n0 + bc);
        float4 b0 = bp4[0], b1v = bp4[1];
        unsigned short bv[8] = {f2bf(b0.x), f2bf(b0.y), f2bf(b0.z), f2bf(b0.w),
                                f2bf(b1v.x), f2bf(b1v.y), f2bf(b1v.z), f2bf(b1v.w)};
#pragma unroll
        for (int j = 0; j < 8; j++) Bs[bc + j][bk] = bv[j];
        __syncthreads();

        bf16x8 af = *(const bf16x8*)(&As[wave * 16 + lm][quad * 8]);
#pragma unroll
        for (int ns = 0; ns < 4; ns++) {
            bf16x8 bf = *(const bf16x8*)(&Bs[ns * 16 + lm][quad * 8]);
            acc[ns] = __builtin_amdgcn_mfma_f32_16x16x32_bf16(af, bf, acc[ns], 0, 0, 0);
        }
        __syncthreads();
    }

    const float* b2e = b2 + (size_t)e * D_MODEL;
#pragma unroll
    for (int ns = 0; ns < 4; ns++) {
        int n = n0 + ns * 16 + lm;
        float bias = b2e[n];
#pragma unroll
        for (int r = 0; r < 4; r++) {
            int m = wave * 16 + quad * 4 + r;
            int tk = toks[m];
            if (tk >= 0) {
                out[(size_t)tk * D_MODEL + n] = (acc[ns][r] + bias) * wgt[tk];
            }
        }
    }
}

// ---------------------------------------------------------------------------
extern "C" void kernel_launch(void* const* d_in, const int* in_sizes, int n_in,
                              void* d_out, int out_size, void* d_ws, size_t ws_size,
                              hipStream_t stream) {
    const float* x  = (const float*)d_in[0];
    const float* Wg = (const float*)d_in[1];
    const float* bg = (const float*)d_in[2];
    const float* W1 = (const float*)d_in[3];
    const float* b1 = (const float*)d_in[4];
    const float* W2 = (const float*)d_in[5];
    const float* b2 = (const float*)d_in[6];
    float* out = (float*)d_out;

    char* ws = (char*)d_ws;
    int*   counts = (int*)ws;                           // 32 B
    float* wgt    = (float*)(ws + 1024);                // 16 KB
    int*   tlist  = (int*)(ws + 32768);                 // 128 KB
    unsigned short* h = (unsigned short*)(ws + 262144); // 33.5 MB bf16

    // ws is re-poisoned to 0xAA before every launch: zero the atomic counters.
    hipMemsetAsync(counts, 0, NUM_EXPERTS * sizeof(int), stream);

    gate_kernel<<<NTOK, 64, 0, stream>>>(x, Wg, bg, counts, tlist, wgt);
    // sum_e ceil(cnt_e/64) <= 71 tile slots; 72 is a safe upper bound.
    ffn1_kernel<<<dim3(D_HIDDEN / 64, 72), 256, 0, stream>>>(x, W1, b1, counts, tlist, h);
    ffn2_kernel<<<dim3(D_MODEL / 64, 72), 256, 0, stream>>>(h, W2, b2, counts, tlist, wgt, out);
}

// Round 3
// 576.157 us; speedup vs baseline: 1.1811x; 1.1811x over previous
//
#include <hip/hip_runtime.h>
#include <stdint.h>

#define D_MODEL 1024
#define D_HIDDEN 4096
#define NUM_EXPERTS 8
#define NTOK 4096  // B*T = 2*2048
#define MAXSLOT 40 // sum_e ceil(cnt_e/128) <= 32+7 = 39

typedef __bf16 bf16x8 __attribute__((ext_vector_type(8)));
typedef float floatx4 __attribute__((ext_vector_type(4)));

static __device__ __forceinline__ unsigned short f2bf(float f) {
    union { float f; unsigned int i; } v;
    v.f = f;
    unsigned int i = v.i;
    unsigned int r = (i + 0x7fffu + ((i >> 16) & 1u)) >> 16;  // RNE
    return (unsigned short)r;
}

// ---------------------------------------------------------------------------
// Gating (fp32): one wave per token, 4 waves/block.
// ---------------------------------------------------------------------------
__global__ __launch_bounds__(256) void gate_kernel(
    const float* __restrict__ x,    // [NTOK][D_MODEL]
    const float* __restrict__ Wg,   // [D_MODEL][NUM_EXPERTS]
    const float* __restrict__ bg,   // [NUM_EXPERTS]
    int* __restrict__ counts,       // [NUM_EXPERTS] (pre-zeroed)
    int* __restrict__ tlist,        // [NUM_EXPERTS][NTOK]
    float* __restrict__ wgt)        // [NTOK]
{
    const int wave = threadIdx.x >> 6;
    const int lane = threadIdx.x & 63;
    const int tok = blockIdx.x * 4 + wave;

    float acc[NUM_EXPERTS];
#pragma unroll
    for (int e = 0; e < NUM_EXPERTS; e++) acc[e] = 0.f;

    const float* xr = x + (size_t)tok * D_MODEL;
    for (int d = lane; d < D_MODEL; d += 64) {
        float xv = xr[d];
        const float4* wr = (const float4*)(Wg + (size_t)d * NUM_EXPERTS);
        float4 w0 = wr[0], w1 = wr[1];
        acc[0] += xv * w0.x; acc[1] += xv * w0.y;
        acc[2] += xv * w0.z; acc[3] += xv * w0.w;
        acc[4] += xv * w1.x; acc[5] += xv * w1.y;
        acc[6] += xv * w1.z; acc[7] += xv * w1.w;
    }
#pragma unroll
    for (int e = 0; e < NUM_EXPERTS; e++) {
        float v = acc[e];
#pragma unroll
        for (int off = 32; off > 0; off >>= 1) v += __shfl_xor(v, off, 64);
        acc[e] = v;
    }
    if (lane == 0) {
        float lg[NUM_EXPERTS];
#pragma unroll
        for (int e = 0; e < NUM_EXPERTS; e++) lg[e] = acc[e] + bg[e];
        int amax = 0;
        float m = lg[0];
#pragma unroll
        for (int e = 1; e < NUM_EXPERTS; e++) {
            if (lg[e] > m) { m = lg[e]; amax = e; }  // first-index-wins
        }
        float s = 0.f;
#pragma unroll
        for (int e = 0; e < NUM_EXPERTS; e++) s += __expf(lg[e] - m);
        wgt[tok] = 1.0f / s;
        int pos = atomicAdd(&counts[amax], 1);
        tlist[amax * NTOK + pos] = tok;
    }
}

// ---------------------------------------------------------------------------
// tile-slot -> (expert, m_tile, count), 128-row granularity.
// ---------------------------------------------------------------------------
__device__ __forceinline__ bool slot_to_expert(const int* counts, int slot,
                                               int& e_out, int& mt_out, int& cnt_out) {
    int cum = 0;
    for (int i = 0; i < NUM_EXPERTS; i++) {
        int c = counts[i];
        int t = (c + 127) >> 7;
        if (slot < cum + t) {
            e_out = i; mt_out = slot - cum; cnt_out = c;
            return true;
        }
        cum += t;
    }
    return false;
}

// ---------------------------------------------------------------------------
// FFN1: h = silu(x @ W1[e] + b1[e]).  128x128 tile, BK=32, 4 waves.
// LDS pitch 40 shorts (80 B = 20 banks): start bank (20n+4g)%32 tiles all
// 32 banks across 8 consecutive lanes -> conflict-free b128 access.
// ---------------------------------------------------------------------------
__global__ __launch_bounds__(256) void ffn1_kernel(
    const float* __restrict__ x,     // [NTOK][D_MODEL]
    const float* __restrict__ W1,    // [E][D_MODEL][D_HIDDEN]
    const float* __restrict__ b1,    // [E][D_HIDDEN]
    const int* __restrict__ counts,
    const int* __restrict__ tlist,
    unsigned short* __restrict__ h)  // [NTOK][D_HIDDEN] bf16
{
    int e, mt, cnt;
    if (!slot_to_expert(counts, blockIdx.y, e, mt, cnt)) return;
    const int n0 = blockIdx.x * 128;

    __shared__ __align__(16) unsigned short As[128][40];  // [m][k]
    __shared__ __align__(16) unsigned short Bs[128][40];  // [n][k]
    __shared__ int toks[128];

    const int tid = threadIdx.x;
    if (tid < 128) {
        int r = mt * 128 + tid;
        toks[tid] = (r < cnt) ? tlist[e * NTOK + r] : -1;
    }
    __syncthreads();

    const int wave = tid >> 6, lane = tid & 63;
    const int quad = lane >> 4, lm = lane & 15;
    const int mo = (wave & 1) * 64, no = (wave >> 1) * 64;

    floatx4 acc[4][4];
#pragma unroll
    for (int i = 0; i < 4; i++)
#pragma unroll
        for (int j = 0; j < 4; j++) acc[i][j] = (floatx4){0.f, 0.f, 0.f, 0.f};

    const float* W1e = W1 + (size_t)e * D_MODEL * D_HIDDEN;

    // A staging: row = tid/2, 16-float half = tid%2
    const int arow = tid >> 1, ahalf = tid & 1;
    int atok = toks[arow];
    const float* aptr = x + (size_t)(atok < 0 ? 0 : atok) * D_MODEL + ahalf * 16;
    // B staging: n-col = tid&127, k-groups g and g+2 where g = tid>>7
    const int bn = tid & 127, bg0 = tid >> 7;

    for (int k0 = 0; k0 < D_MODEL; k0 += 32) {
        // --- A tile: 16 fp32 -> 16 bf16 -> 2x ds_write_b128
        float4 a4[4];
#pragma unroll
        for (int i = 0; i < 4; i++) a4[i] = ((const float4*)(aptr + k0))[i];
        unsigned short av[16];
#pragma unroll
        for (int i = 0; i < 4; i++) {
            av[i * 4 + 0] = f2bf(a4[i].x); av[i * 4 + 1] = f2bf(a4[i].y);
            av[i * 4 + 2] = f2bf(a4[i].z); av[i * 4 + 3] = f2bf(a4[i].w);
        }
        *(uint4*)(&As[arow][ahalf * 16])     = ((const uint4*)av)[0];
        *(uint4*)(&As[arow][ahalf * 16 + 8]) = ((const uint4*)av)[1];

        // --- B tile transpose: per task, 8 k-strided loads for one n-col
#pragma unroll
        for (int t = 0; t < 2; t++) {
            int g = bg0 + t * 2;
            const float* bp = W1e + (size_t)(k0 + g * 8) * D_HIDDEN + n0 + bn;
            unsigned short bv[8];
#pragma unroll
            for (int j = 0; j < 8; j++) bv[j] = f2bf(bp[(size_t)j * D_HIDDEN]);
            *(uint4*)(&Bs[bn][g * 8]) = *(const uint4*)bv;
        }
        __syncthreads();

        bf16x8 af[4], bfr[4];
#pragma unroll
        for (int i = 0; i < 4; i++) {
            af[i]  = *(const bf16x8*)(&As[mo + i * 16 + lm][quad * 8]);
            bfr[i] = *(const bf16x8*)(&Bs[no + i * 16 + lm][quad * 8]);
        }
#pragma unroll
        for (int mi = 0; mi < 4; mi++)
#pragma unroll
            for (int ni = 0; ni < 4; ni++)
                acc[mi][ni] = __builtin_amdgcn_mfma_f32_16x16x32_bf16(
                    af[mi], bfr[ni], acc[mi][ni], 0, 0, 0);
        __syncthreads();
    }

    const float* b1e = b1 + (size_t)e * D_HIDDEN;
#pragma unroll
    for (int ni = 0; ni < 4; ni++) {
        int n = n0 + no + ni * 16 + lm;
        float bias = b1e[n];
#pragma unroll
        for (int mi = 0; mi < 4; mi++)
#pragma unroll
            for (int r = 0; r < 4; r++) {
                int m = mo + mi * 16 + quad * 4 + r;
                int tk = toks[m];
                if (tk >= 0) {
                    float z = acc[mi][ni][r] + bias;
                    h[(size_t)tk * D_HIDDEN + n] = f2bf(z / (1.f + __expf(-z)));
                }
            }
    }
}

// ---------------------------------------------------------------------------
// FFN2: y = (h @ W2[e] + b2[e]) * w.  Same structure; A already bf16.
// ---------------------------------------------------------------------------
__global__ __launch_bounds__(256) void ffn2_kernel(
    const unsigned short* __restrict__ h,  // [NTOK][D_HIDDEN] bf16
    const float* __restrict__ W2,          // [E][D_HIDDEN][D_MODEL]
    const float* __restrict__ b2,          // [E][D_MODEL]
    const int* __restrict__ counts,
    const int* __restrict__ tlist,
    const float* __restrict__ wgt,
    float* __restrict__ out)               // [NTOK][D_MODEL] fp32
{
    int e, mt, cnt;
    if (!slot_to_expert(counts, blockIdx.y, e, mt, cnt)) return;
    const int n0 = blockIdx.x * 128;

    __shared__ __align__(16) unsigned short As[128][40];
    __shared__ __align__(16) unsigned short Bs[128][40];
    __shared__ int toks[128];

    const int tid = threadIdx.x;
    if (tid < 128) {
        int r = mt * 128 + tid;
        toks[tid] = (r < cnt) ? tlist[e * NTOK + r] : -1;
    }
    __syncthreads();

    const int wave = tid >> 6, lane = tid & 63;
    const int quad = lane >> 4, lm = lane & 15;
    const int mo = (wave & 1) * 64, no = (wave >> 1) * 64;

    floatx4 acc[4][4];
#pragma unroll
    for (int i = 0; i < 4; i++)
#pragma unroll
        for (int j = 0; j < 4; j++) acc[i][j] = (floatx4){0.f, 0.f, 0.f, 0.f};

    const float* W2e = W2 + (size_t)e * D_HIDDEN * D_MODEL;

    const int arow = tid >> 1, ahalf = tid & 1;
    int atok = toks[arow];
    const unsigned short* aptr =
        h + (size_t)(atok < 0 ? 0 : atok) * D_HIDDEN + ahalf * 16;
    const int bn = tid & 127, bg0 = tid >> 7;

    for (int k0 = 0; k0 < D_HIDDEN; k0 += 32) {
        // --- A tile: already bf16, 2x 16B copies
        uint4 a0 = *(const uint4*)(aptr + k0);
        uint4 a1 = *(const uint4*)(aptr + k0 + 8);
        *(uint4*)(&As[arow][ahalf * 16])     = a0;
        *(uint4*)(&As[arow][ahalf * 16 + 8]) = a1;

        // --- B tile transpose
#pragma unroll
        for (int t = 0; t < 2; t++) {
            int g = bg0 + t * 2;
            const float* bp = W2e + (size_t)(k0 + g * 8) * D_MODEL + n0 + bn;
            unsigned short bv[8];
#pragma unroll
            for (int j = 0; j < 8; j++) bv[j] = f2bf(bp[(size_t)j * D_MODEL]);
            *(uint4*)(&Bs[bn][g * 8]) = *(const uint4*)bv;
        }
        __syncthreads();

        bf16x8 af[4], bfr[4];
#pragma unroll
        for (int i = 0; i < 4; i++) {
            af[i]  = *(const bf16x8*)(&As[mo + i * 16 + lm][quad * 8]);
            bfr[i] = *(const bf16x8*)(&Bs[no + i * 16 + lm][quad * 8]);
        }
#pragma unroll
        for (int mi = 0; mi < 4; mi++)
#pragma unroll
            for (int ni = 0; ni < 4; ni++)
                acc[mi][ni] = __builtin_amdgcn_mfma_f32_16x16x32_bf16(
                    af[mi], bfr[ni], acc[mi][ni], 0, 0, 0);
        __syncthreads();
    }

    const float* b2e = b2 + (size_t)e * D_MODEL;
#pragma unroll
    for (int ni = 0; ni < 4; ni++) {
        int n = n0 + no + ni * 16 + lm;
        float bias = b2e[n];
#pragma unroll
        for (int mi = 0; mi < 4; mi++)
#pragma unroll
            for (int r = 0; r < 4; r++) {
                int m = mo + mi * 16 + quad * 4 + r;
                int tk = toks[m];
                if (tk >= 0) {
                    out[(size_t)tk * D_MODEL + n] = (acc[mi][ni][r] + bias) * wgt[tk];
                }
            }
    }
}

// ---------------------------------------------------------------------------
extern "C" void kernel_launch(void* const* d_in, const int* in_sizes, int n_in,
                              void* d_out, int out_size, void* d_ws, size_t ws_size,
                              hipStream_t stream) {
    const float* x  = (const float*)d_in[0];
    const float* Wg = (const float*)d_in[1];
    const float* bg = (const float*)d_in[2];
    const float* W1 = (const float*)d_in[3];
    const float* b1 = (const float*)d_in[4];
    const float* W2 = (const float*)d_in[5];
    const float* b2 = (const float*)d_in[6];
    float* out = (float*)d_out;

    char* ws = (char*)d_ws;
    int*   counts = (int*)ws;                           // 32 B
    float* wgt    = (float*)(ws + 1024);                // 16 KB
    int*   tlist  = (int*)(ws + 32768);                 // 128 KB
    unsigned short* h = (unsigned short*)(ws + 262144); // 33.5 MB bf16

    hipMemsetAsync(counts, 0, NUM_EXPERTS * sizeof(int), stream);

    gate_kernel<<<NTOK / 4, 256, 0, stream>>>(x, Wg, bg, counts, tlist, wgt);
    ffn1_kernel<<<dim3(D_HIDDEN / 128, MAXSLOT), 256, 0, stream>>>(x, W1, b1, counts, tlist, h);
    ffn2_kernel<<<dim3(D_MODEL / 128, MAXSLOT), 256, 0, stream>>>(h, W2, b2, counts, tlist, wgt, out);
}

// Round 4
// 574.676 us; speedup vs baseline: 1.1842x; 1.0026x over previous
//
#include <hip/hip_runtime.h>
#include <stdint.h>

#define D_MODEL 1024
#define D_HIDDEN 4096
#define NUM_EXPERTS 8
#define NTOK 4096  // B*T = 2*2048
#define MAXSLOT 40 // sum_e ceil(cnt_e/128) <= 32+7 = 39
#define KSPLIT 4   // ffn2 split-K chunks (K=4096 -> 1024 each)

typedef __bf16 bf16x8 __attribute__((ext_vector_type(8)));
typedef float floatx4 __attribute__((ext_vector_type(4)));

static __device__ __forceinline__ unsigned short f2bf(float f) {
    union { float f; unsigned int i; } v;
    v.f = f;
    unsigned int i = v.i;
    unsigned int r = (i + 0x7fffu + ((i >> 16) & 1u)) >> 16;  // RNE
    return (unsigned short)r;
}

// ---------------------------------------------------------------------------
// Gating (fp32): one wave per token, 4 waves/block.
// ---------------------------------------------------------------------------
__global__ __launch_bounds__(256) void gate_kernel(
    const float* __restrict__ x,    // [NTOK][D_MODEL]
    const float* __restrict__ Wg,   // [D_MODEL][NUM_EXPERTS]
    const float* __restrict__ bg,   // [NUM_EXPERTS]
    int* __restrict__ counts,       // [NUM_EXPERTS] (pre-zeroed)
    int* __restrict__ tlist,        // [NUM_EXPERTS][NTOK]
    float* __restrict__ wgt)        // [NTOK]
{
    const int wave = threadIdx.x >> 6;
    const int lane = threadIdx.x & 63;
    const int tok = blockIdx.x * 4 + wave;

    float acc[NUM_EXPERTS];
#pragma unroll
    for (int e = 0; e < NUM_EXPERTS; e++) acc[e] = 0.f;

    const float* xr = x + (size_t)tok * D_MODEL;
    for (int d = lane; d < D_MODEL; d += 64) {
        float xv = xr[d];
        const float4* wr = (const float4*)(Wg + (size_t)d * NUM_EXPERTS);
        float4 w0 = wr[0], w1 = wr[1];
        acc[0] += xv * w0.x; acc[1] += xv * w0.y;
        acc[2] += xv * w0.z; acc[3] += xv * w0.w;
        acc[4] += xv * w1.x; acc[5] += xv * w1.y;
        acc[6] += xv * w1.z; acc[7] += xv * w1.w;
    }
#pragma unroll
    for (int e = 0; e < NUM_EXPERTS; e++) {
        float v = acc[e];
#pragma unroll
        for (int off = 32; off > 0; off >>= 1) v += __shfl_xor(v, off, 64);
        acc[e] = v;
    }
    if (lane == 0) {
        float lg[NUM_EXPERTS];
#pragma unroll
        for (int e = 0; e < NUM_EXPERTS; e++) lg[e] = acc[e] + bg[e];
        int amax = 0;
        float m = lg[0];
#pragma unroll
        for (int e = 1; e < NUM_EXPERTS; e++) {
            if (lg[e] > m) { m = lg[e]; amax = e; }  // first-index-wins
        }
        float s = 0.f;
#pragma unroll
        for (int e = 0; e < NUM_EXPERTS; e++) s += __expf(lg[e] - m);
        wgt[tok] = 1.0f / s;
        int pos = atomicAdd(&counts[amax], 1);
        tlist[amax * NTOK + pos] = tok;
    }
}

// ---------------------------------------------------------------------------
// tile-slot -> (expert, m_tile, count), 128-row granularity.
// ---------------------------------------------------------------------------
__device__ __forceinline__ bool slot_to_expert(const int* counts, int slot,
                                               int& e_out, int& mt_out, int& cnt_out) {
    int cum = 0;
    for (int i = 0; i < NUM_EXPERTS; i++) {
        int c = counts[i];
        int t = (c + 127) >> 7;
        if (slot < cum + t) {
            e_out = i; mt_out = slot - cum; cnt_out = c;
            return true;
        }
        cum += t;
    }
    return false;
}

// ---------------------------------------------------------------------------
// FFN1: h = silu(x @ W1[e] + b1[e]).  128x128 tile, BK=32, 4 waves.
// LDS pitch 40 shorts (80 B = 20 banks) -> conflict-free b128 access.
// ---------------------------------------------------------------------------
__global__ __launch_bounds__(256) void ffn1_kernel(
    const float* __restrict__ x,     // [NTOK][D_MODEL]
    const float* __restrict__ W1,    // [E][D_MODEL][D_HIDDEN]
    const float* __restrict__ b1,    // [E][D_HIDDEN]
    const int* __restrict__ counts,
    const int* __restrict__ tlist,
    unsigned short* __restrict__ h)  // [NTOK][D_HIDDEN] bf16
{
    int e, mt, cnt;
    if (!slot_to_expert(counts, blockIdx.y, e, mt, cnt)) return;
    const int n0 = blockIdx.x * 128;

    __shared__ __align__(16) unsigned short As[128][40];  // [m][k]
    __shared__ __align__(16) unsigned short Bs[128][40];  // [n][k]
    __shared__ int toks[128];

    const int tid = threadIdx.x;
    if (tid < 128) {
        int r = mt * 128 + tid;
        toks[tid] = (r < cnt) ? tlist[e * NTOK + r] : -1;
    }
    __syncthreads();

    const int wave = tid >> 6, lane = tid & 63;
    const int quad = lane >> 4, lm = lane & 15;
    const int mo = (wave & 1) * 64, no = (wave >> 1) * 64;

    floatx4 acc[4][4];
#pragma unroll
    for (int i = 0; i < 4; i++)
#pragma unroll
        for (int j = 0; j < 4; j++) acc[i][j] = (floatx4){0.f, 0.f, 0.f, 0.f};

    const float* W1e = W1 + (size_t)e * D_MODEL * D_HIDDEN;

    const int arow = tid >> 1, ahalf = tid & 1;
    int atok = toks[arow];
    const float* aptr = x + (size_t)(atok < 0 ? 0 : atok) * D_MODEL + ahalf * 16;
    const int bn = tid & 127, bg0 = tid >> 7;

    for (int k0 = 0; k0 < D_MODEL; k0 += 32) {
        float4 a4[4];
#pragma unroll
        for (int i = 0; i < 4; i++) a4[i] = ((const float4*)(aptr + k0))[i];
        unsigned short av[16];
#pragma unroll
        for (int i = 0; i < 4; i++) {
            av[i * 4 + 0] = f2bf(a4[i].x); av[i * 4 + 1] = f2bf(a4[i].y);
            av[i * 4 + 2] = f2bf(a4[i].z); av[i * 4 + 3] = f2bf(a4[i].w);
        }
        *(uint4*)(&As[arow][ahalf * 16])     = ((const uint4*)av)[0];
        *(uint4*)(&As[arow][ahalf * 16 + 8]) = ((const uint4*)av)[1];

#pragma unroll
        for (int t = 0; t < 2; t++) {
            int g = bg0 + t * 2;
            const float* bp = W1e + (size_t)(k0 + g * 8) * D_HIDDEN + n0 + bn;
            unsigned short bv[8];
#pragma unroll
            for (int j = 0; j < 8; j++) bv[j] = f2bf(bp[(size_t)j * D_HIDDEN]);
            *(uint4*)(&Bs[bn][g * 8]) = *(const uint4*)bv;
        }
        __syncthreads();

        bf16x8 af[4], bfr[4];
#pragma unroll
        for (int i = 0; i < 4; i++) {
            af[i]  = *(const bf16x8*)(&As[mo + i * 16 + lm][quad * 8]);
            bfr[i] = *(const bf16x8*)(&Bs[no + i * 16 + lm][quad * 8]);
        }
#pragma unroll
        for (int mi = 0; mi < 4; mi++)
#pragma unroll
            for (int ni = 0; ni < 4; ni++)
                acc[mi][ni] = __builtin_amdgcn_mfma_f32_16x16x32_bf16(
                    af[mi], bfr[ni], acc[mi][ni], 0, 0, 0);
        __syncthreads();
    }

    const float* b1e = b1 + (size_t)e * D_HIDDEN;
#pragma unroll
    for (int ni = 0; ni < 4; ni++) {
        int n = n0 + no + ni * 16 + lm;
        float bias = b1e[n];
#pragma unroll
        for (int mi = 0; mi < 4; mi++)
#pragma unroll
            for (int r = 0; r < 4; r++) {
                int m = mo + mi * 16 + quad * 4 + r;
                int tk = toks[m];
                if (tk >= 0) {
                    float z = acc[mi][ni][r] + bias;
                    h[(size_t)tk * D_HIDDEN + n] = f2bf(z / (1.f + __expf(-z)));
                }
            }
    }
}

// ---------------------------------------------------------------------------
// FFN2 (split-K): partial = h[:,kc] @ W2[e][kc,:]; atomicAdd (partial
// + (kc==0)*b2) * wgt into out.  Grid z = k-chunk.
// ---------------------------------------------------------------------------
__global__ __launch_bounds__(256) void ffn2_kernel(
    const unsigned short* __restrict__ h,  // [NTOK][D_HIDDEN] bf16
    const float* __restrict__ W2,          // [E][D_HIDDEN][D_MODEL]
    const float* __restrict__ b2,          // [E][D_MODEL]
    const int* __restrict__ counts,
    const int* __restrict__ tlist,
    const float* __restrict__ wgt,
    float* __restrict__ out)               // [NTOK][D_MODEL] fp32 (pre-zeroed)
{
    int e, mt, cnt;
    if (!slot_to_expert(counts, blockIdx.y, e, mt, cnt)) return;
    const int n0 = blockIdx.x * 128;
    const int kc = blockIdx.z;
    const int kbeg = kc * (D_HIDDEN / KSPLIT);
    const int kend = kbeg + (D_HIDDEN / KSPLIT);

    __shared__ __align__(16) unsigned short As[128][40];
    __shared__ __align__(16) unsigned short Bs[128][40];
    __shared__ int toks[128];

    const int tid = threadIdx.x;
    if (tid < 128) {
        int r = mt * 128 + tid;
        toks[tid] = (r < cnt) ? tlist[e * NTOK + r] : -1;
    }
    __syncthreads();

    const int wave = tid >> 6, lane = tid & 63;
    const int quad = lane >> 4, lm = lane & 15;
    const int mo = (wave & 1) * 64, no = (wave >> 1) * 64;

    floatx4 acc[4][4];
#pragma unroll
    for (int i = 0; i < 4; i++)
#pragma unroll
        for (int j = 0; j < 4; j++) acc[i][j] = (floatx4){0.f, 0.f, 0.f, 0.f};

    const float* W2e = W2 + (size_t)e * D_HIDDEN * D_MODEL;

    const int arow = tid >> 1, ahalf = tid & 1;
    int atok = toks[arow];
    const unsigned short* aptr =
        h + (size_t)(atok < 0 ? 0 : atok) * D_HIDDEN + ahalf * 16;
    const int bn = tid & 127, bg0 = tid >> 7;

    for (int k0 = kbeg; k0 < kend; k0 += 32) {
        uint4 a0 = *(const uint4*)(aptr + k0);
        uint4 a1 = *(const uint4*)(aptr + k0 + 8);
        *(uint4*)(&As[arow][ahalf * 16])     = a0;
        *(uint4*)(&As[arow][ahalf * 16 + 8]) = a1;

#pragma unroll
        for (int t = 0; t < 2; t++) {
            int g = bg0 + t * 2;
            const float* bp = W2e + (size_t)(k0 + g * 8) * D_MODEL + n0 + bn;
            unsigned short bv[8];
#pragma unroll
            for (int j = 0; j < 8; j++) bv[j] = f2bf(bp[(size_t)j * D_MODEL]);
            *(uint4*)(&Bs[bn][g * 8]) = *(const uint4*)bv;
        }
        __syncthreads();

        bf16x8 af[4], bfr[4];
#pragma unroll
        for (int i = 0; i < 4; i++) {
            af[i]  = *(const bf16x8*)(&As[mo + i * 16 + lm][quad * 8]);
            bfr[i] = *(const bf16x8*)(&Bs[no + i * 16 + lm][quad * 8]);
        }
#pragma unroll
        for (int mi = 0; mi < 4; mi++)
#pragma unroll
            for (int ni = 0; ni < 4; ni++)
                acc[mi][ni] = __builtin_amdgcn_mfma_f32_16x16x32_bf16(
                    af[mi], bfr[ni], acc[mi][ni], 0, 0, 0);
        __syncthreads();
    }

    const float* b2e = b2 + (size_t)e * D_MODEL;
#pragma unroll
    for (int ni = 0; ni < 4; ni++) {
        int n = n0 + no + ni * 16 + lm;
        float bias = (kc == 0) ? b2e[n] : 0.f;
#pragma unroll
        for (int mi = 0; mi < 4; mi++)
#pragma unroll
            for (int r = 0; r < 4; r++) {
                int m = mo + mi * 16 + quad * 4 + r;
                int tk = toks[m];
                if (tk >= 0) {
                    atomicAdd(&out[(size_t)tk * D_MODEL + n],
                              (acc[mi][ni][r] + bias) * wgt[tk]);
                }
            }
    }
}

// ---------------------------------------------------------------------------
extern "C" void kernel_launch(void* const* d_in, const int* in_sizes, int n_in,
                              void* d_out, int out_size, void* d_ws, size_t ws_size,
                              hipStream_t stream) {
    const float* x  = (const float*)d_in[0];
    const float* Wg = (const float*)d_in[1];
    const float* bg = (const float*)d_in[2];
    const float* W1 = (const float*)d_in[3];
    const float* b1 = (const float*)d_in[4];
    const float* W2 = (const float*)d_in[5];
    const float* b2 = (const float*)d_in[6];
    float* out = (float*)d_out;

    char* ws = (char*)d_ws;
    int*   counts = (int*)ws;                           // 32 B
    float* wgt    = (float*)(ws + 1024);                // 16 KB
    int*   tlist  = (int*)(ws + 32768);                 // 128 KB
    unsigned short* h = (unsigned short*)(ws + 262144); // 33.5 MB bf16

    hipMemsetAsync(counts, 0, NUM_EXPERTS * sizeof(int), stream);
    hipMemsetAsync(out, 0, (size_t)out_size * sizeof(float), stream);  // split-K accum target

    gate_kernel<<<NTOK / 4, 256, 0, stream>>>(x, Wg, bg, counts, tlist, wgt);
    ffn1_kernel<<<dim3(D_HIDDEN / 128, MAXSLOT), 256, 0, stream>>>(x, W1, b1, counts, tlist, h);
    ffn2_kernel<<<dim3(D_MODEL / 128, MAXSLOT, KSPLIT), 256, 0, stream>>>(h, W2, b2, counts, tlist, wgt, out);
}